// Round 6
// baseline (548.076 us; speedup 1.0000x reference)
//
#include <hip/hip_runtime.h>
#include <hip/hip_bf16.h>
#include <stdint.h>

typedef __bf16 bf16_t;
typedef __bf16 bf16x8 __attribute__((ext_vector_type(8)));
typedef float f32x4 __attribute__((ext_vector_type(4)));

#define LOG2E 1.44269504088896340736f
#define LN2 0.69314718055994530942f

__device__ __forceinline__ float fast_exp2(float x) { return __builtin_amdgcn_exp2f(x); }
__device__ __forceinline__ float fast_log2(float x) { return __builtin_amdgcn_logf(x); }
__device__ __forceinline__ float fast_rcp(float x) { return __builtin_amdgcn_rcpf(x); }

// arg already scaled by LOG2E: returns softplus(x) where t = x*LOG2E
__device__ __forceinline__ float softplus_t(float t) {
    float sp = LN2 * fast_log2(1.0f + fast_exp2(t));
    return (t > 28.9f) ? t * LN2 : sp;
}
// arg already scaled by 2*LOG2E: returns tanh(x) where t = 2x*LOG2E
__device__ __forceinline__ float tanh_t(float t) {
    float e = fast_exp2(t);
    return 1.0f - 2.0f * fast_rcp(1.0f + e);
}

// single-instruction f32->bf16 (RNE); result in low 16 bits
__device__ __forceinline__ uint32_t cvt_bf16(float a) {
    uint32_t r;
    asm("v_cvt_pk_bf16_f32 %0, %1, %2" : "=v"(r) : "v"(a), "v"(a));
    return r;
}
__device__ __forceinline__ void pack_bf16(float v, uint16_t* ph, uint16_t* pl) {
    uint32_t h = cvt_bf16(v);
    float hf = __builtin_bit_cast(float, h << 16);
    uint32_t lo = cvt_bf16(v - hf);
    *ph = (uint16_t)h;
    *pl = (uint16_t)lo;
}

template <int CTRL>
__device__ __forceinline__ float dpp_add(float v) {
    int iv = __builtin_bit_cast(int, v);
    int sv = __builtin_amdgcn_update_dpp(0, iv, CTRL, 0xF, 0xF, true);
    return v + __builtin_bit_cast(float, sv);
}
// full 8-lane-group sum, result in ALL 8 lanes
__device__ __forceinline__ float red8(float v) {
    v = dpp_add<0xB1>(v);   // + lane^1
    v = dpp_add<0x4E>(v);   // + lane^2
    v = dpp_add<0x141>(v);  // + mirrored half-row
    return v;
}

// B=4096, L=64, C=7, H=32, K=2 -> 126 RK4 steps, h=0.5
// Block: 256 threads (4 waves, 1/SIMD), owns 16 batch rows. Grid: 256 blocks.
// 2 barriers/stage. Phase A: dxs + GEMV1 (1 tile, 2 regs per wave).
// Phase B: GEMV2 (4 tiles/wave) + tanh + 8-lane reduce + 2 duty z/lane.
__global__ __launch_bounds__(256, 1) void cde_kernel(
    const float* __restrict__ x,    // (4096,64,7)
    const float* __restrict__ Wi,   // (32,7)
    const float* __restrict__ bi,   // (32,)
    const float* __restrict__ W1,   // (32,32)
    const float* __restrict__ b1,   // (32,)
    const float* __restrict__ W2,   // (224,32)
    const float* __restrict__ b2,   // (224,)
    const float* __restrict__ Wo1,  // (16,32)
    const float* __restrict__ bo1,  // (16,)
    const float* __restrict__ Wo2,  // (3,16)
    const float* __restrict__ bo2,  // (3,)
    float* __restrict__ out)        // (4096,3)
{
    __shared__ float diffs[16][441];                    // [batch][i*7+c]
    __shared__ float dxsT[8][20];                       // [c][batch]; row 7 = 0 pad
    __shared__ uint16_t zhiu[4][16][8], zlou[4][16][8]; // [h-chunk][batch][h-pos]
    __shared__ uint16_t h1hiu[4][16][8], h1lou[4][16][8];
    __shared__ float zfin[16][32];                      // [batch][h]
    __shared__ float wo1t[32][16];
    __shared__ float ubuf[16][16];

    const int tid = threadIdx.x;
    const int l = tid & 63;
    const int w = tid >> 6;          // wave 0..3
    const int r0 = blockIdx.x * 16;

    const int ar = l & 15;           // MFMA A-row (batch) / B-col / D-col
    const int chunk = l >> 4;        // k-chunk 0..3
    const int ak = chunk * 8;
    const int crow = chunk * 4;      // D row base (batch)
    const int g = l & 7;             // c column / group position

    // Phase-A duty: wave w -> tile T1 = w>>1, regs {rA, rA+1}
    const int T1 = w >> 1;
    const int rA = 2 * (w & 1);
    const int h1col = 16 * T1 + ar;
    const bool lowpair = (w & 1) == 0;

    // Phase-B duty: lane owns 2 k-values (batch drow0/1, h dcol)
    const int hb = (l >> 3) & 1;
    const int dcol = 8 * w + 2 * (g >> 1) + hb;      // h index 0..31
    const int drow0 = crow + 2 * (g & 1);            // batch
    const int drow1 = drow0 + 1;
    const bool selr = (g & 1) != 0;
    const bool sj1 = (g & 2) != 0;
    const bool sj2 = (g & 4) != 0;

    // hoisted LDS pointers
    const bf16x8* pZh = (const bf16x8*)&zhiu[chunk][ar][0];
    const bf16x8* pZl = (const bf16x8*)&zlou[chunk][ar][0];
    const bf16x8* pHh = (const bf16x8*)&h1hiu[chunk][ar][0];
    const bf16x8* pHl = (const bf16x8*)&h1lou[chunk][ar][0];
    const f32x4* pDx = (const f32x4*)&dxsT[g][crow];
    uint16_t* pH0h = &h1hiu[h1col >> 3][crow + rA][h1col & 7];
    uint16_t* pH0l = &h1lou[h1col >> 3][crow + rA][h1col & 7];
    uint16_t* pH1h = &h1hiu[h1col >> 3][crow + rA + 1][h1col & 7];
    uint16_t* pH1l = &h1lou[h1col >> 3][crow + rA + 1][h1col & 7];
    uint16_t* pZ0h = &zhiu[dcol >> 3][drow0][dcol & 7];
    uint16_t* pZ0l = &zlou[dcol >> 3][drow0][dcol & 7];
    uint16_t* pZ1h = &zhiu[dcol >> 3][drow1][dcol & 7];
    uint16_t* pZ1l = &zlou[dcol >> 3][drow1][dcol & 7];

    // ---- weight fragments (pre-scaled; hi/lo bf16 split) ----
    bf16x8 w1h, w1l;    // tile T1, scaled by LOG2E
    {
        const float* p = &W1[h1col * 32 + ak];
#pragma unroll
        for (int j = 0; j < 8; ++j) {
            float v = p[j] * LOG2E;
            bf16_t hh = (bf16_t)v;
            w1h[j] = hh;
            w1l[j] = (bf16_t)(v - (float)hh);
        }
    }
    const float b1c = b1[h1col] * LOG2E;

    bf16x8 w2h[4], w2l[4];   // 4 tiles, scaled by 2*LOG2E
    float b2c[4];
    const bool cvalid = (ar & 7) < 7;
#pragma unroll
    for (int j = 0; j < 4; ++j) {
        int hcol = 8 * w + 2 * j + (ar >> 3);
        int ccol = ar & 7;
        if (cvalid) {
            const float* p = &W2[(hcol * 7 + ccol) * 32 + ak];
#pragma unroll
            for (int q = 0; q < 8; ++q) {
                float v = p[q] * (2.0f * LOG2E);
                bf16_t hh = (bf16_t)v;
                w2h[j][q] = hh;
                w2l[j][q] = (bf16_t)(v - (float)hh);
            }
            b2c[j] = b2[hcol * 7 + ccol] * (2.0f * LOG2E);
        } else {
#pragma unroll
            for (int q = 0; q < 8; ++q) { w2h[j][q] = (bf16_t)0.0f; w2l[j][q] = (bf16_t)0.0f; }
            b2c[j] = 0.0f;
        }
    }

    // ---- spline diffs into LDS ----
    for (int e = tid; e < 16 * 441; e += 256) {
        int r = e / 441, rem = e - r * 441;
        const float* px = &x[(size_t)(r0 + r) * 448];
        diffs[r][rem] = px[rem + 7] - px[rem];
    }
    // ---- z0 = x[:,0] @ Wi^T + bi ----
#pragma unroll
    for (int e0 = 0; e0 < 2; ++e0) {
        int e = tid + e0 * 256;
        int r = e >> 5, hh = e & 31;
        const float* px = &x[(size_t)(r0 + r) * 448];
        float acc = bi[hh];
#pragma unroll
        for (int c = 0; c < 7; ++c) acc += px[c] * Wi[hh * 7 + c];
        zfin[r][hh] = acc;
        pack_bf16(acc, &zhiu[hh >> 3][r][hh & 7], &zlou[hh >> 3][r][hh & 7]);
    }
    if (tid < 16) dxsT[7][tid] = 0.0f;   // padded-c column contributes 0
    __syncthreads();

    // duty-lane RK4 state (2 per lane)
    float zb0 = zfin[drow0][dcol];
    float zb1 = zfin[drow1][dcol];
    float ka0 = 0.0f, ka1 = 0.0f;

    for (int it = 0; it < 504; ++it) {
        const int s = it & 3;
        const int k = it >> 2;

        // ---------- phase A: dxs + GEMV1 ----------
        if (s != 2 && (l & 15) < 7) {      // k2,k3 share t+h/2
            int rdx = w + 4 * (l >> 4);    // 4 rows per wave
            int cdx = l & 15;
            int m = 2 * k + (s == 0 ? 0 : (s == 3 ? 2 : 1));   // t = 0.25*m
            int i = m >> 2; if (i > 62) i = 62;
            float f = 0.25f * (float)(m - 4 * i);
            float D = diffs[rdx][i * 7 + cdx];
            float a = diffs[rdx][(i > 0 ? i - 1 : 0) * 7 + cdx];
            dxsT[cdx][rdx] = a + (D - a) * (f * (4.0f - 3.0f * f));
        }
        {
            bf16x8 azh = *pZh;
            bf16x8 azl = *pZl;
            f32x4 zero4 = {0.0f, 0.0f, 0.0f, 0.0f};
            f32x4 b14 = {b1c, b1c, b1c, b1c};
            f32x4 d1a = __builtin_amdgcn_mfma_f32_16x16x32_bf16(azh, w1h, b14, 0, 0, 0);
            f32x4 d1b = __builtin_amdgcn_mfma_f32_16x16x32_bf16(azl, w1h, zero4, 0, 0, 0);
            f32x4 d1c = __builtin_amdgcn_mfma_f32_16x16x32_bf16(azh, w1l, zero4, 0, 0, 0);
            float y0 = (lowpair ? d1a[0] : d1a[2]) + (lowpair ? d1b[0] : d1b[2]) +
                       (lowpair ? d1c[0] : d1c[2]);
            float y1 = (lowpair ? d1a[1] : d1a[3]) + (lowpair ? d1b[1] : d1b[3]) +
                       (lowpair ? d1c[1] : d1c[3]);
            pack_bf16(softplus_t(y0), pH0h, pH0l);
            pack_bf16(softplus_t(y1), pH1h, pH1l);
        }
        __syncthreads();

        // ---------- phase B: GEMV2 + tanh + reduce + duty RK4 ----------
        {
            bf16x8 ahh = *pHh;
            bf16x8 ahl = *pHl;
            f32x4 dxv = *pDx;            // dx[batch crow..crow+3][c=g]
            float vr[4][4];
#pragma unroll
            for (int j = 0; j < 4; ++j) {
                f32x4 d2 = {b2c[j], b2c[j], b2c[j], b2c[j]};
                d2 = __builtin_amdgcn_mfma_f32_16x16x32_bf16(ahh, w2h[j], d2, 0, 0, 0);
                d2 = __builtin_amdgcn_mfma_f32_16x16x32_bf16(ahl, w2h[j], d2, 0, 0, 0);
                d2 = __builtin_amdgcn_mfma_f32_16x16x32_bf16(ahh, w2l[j], d2, 0, 0, 0);
#pragma unroll
                for (int r = 0; r < 4; ++r)
                    vr[j][r] = red8(tanh_t(d2[r]) * dxv[r]);
            }
            // duty select: va = vr[g>>1][2(g&1)], vb = vr[g>>1][2(g&1)+1]
            float u0 = selr ? vr[0][2] : vr[0][0];
            float u1 = selr ? vr[1][2] : vr[1][0];
            float u2 = selr ? vr[2][2] : vr[2][0];
            float u3 = selr ? vr[3][2] : vr[3][0];
            float va = sj2 ? (sj1 ? u3 : u2) : (sj1 ? u1 : u0);
            float q0 = selr ? vr[0][3] : vr[0][1];
            float q1 = selr ? vr[1][3] : vr[1][1];
            float q2 = selr ? vr[2][3] : vr[2][1];
            float q3 = selr ? vr[3][3] : vr[3][1];
            float vb = sj2 ? (sj1 ? q3 : q2) : (sj1 ? q1 : q0);

            float zs0, zs1;
            if (s == 0) {
                ka0 = va; ka1 = vb;
                zs0 = zb0 + 0.25f * va; zs1 = zb1 + 0.25f * vb;
            } else if (s == 1) {
                ka0 += 2.0f * va; ka1 += 2.0f * vb;
                zs0 = zb0 + 0.25f * va; zs1 = zb1 + 0.25f * vb;
            } else if (s == 2) {
                ka0 += 2.0f * va; ka1 += 2.0f * vb;
                zs0 = zb0 + 0.5f * va; zs1 = zb1 + 0.5f * vb;
            } else {
                zb0 += (1.0f / 12.0f) * (ka0 + va);
                zb1 += (1.0f / 12.0f) * (ka1 + vb);
                zs0 = zb0; zs1 = zb1;
            }
            pack_bf16(zs0, pZ0h, pZ0l);
            pack_bf16(zs1, pZ1h, pZ1l);
        }
        __syncthreads();
    }

    // ---- epilogue: out = softplus(z @ Wo1^T + bo1) @ Wo2^T + bo2 ----
    zfin[drow0][dcol] = zb0;
    zfin[drow1][dcol] = zb1;
#pragma unroll
    for (int e0 = 0; e0 < 2; ++e0) {
        int e = tid + e0 * 256;
        int hh = e >> 4, jj = e & 15;
        wo1t[hh][jj] = Wo1[jj * 32 + hh];
    }
    __syncthreads();
    {
        int r = tid >> 4, jj = tid & 15;
        float acc = bo1[jj];
#pragma unroll
        for (int hh = 0; hh < 32; ++hh) acc += zfin[r][hh] * wo1t[hh][jj];
        ubuf[r][jj] = softplus_t(acc * LOG2E);
    }
    __syncthreads();
    if (tid < 48) {
        int r = tid / 3, o = tid - (tid / 3) * 3;
        float acc = bo2[o];
#pragma unroll
        for (int j = 0; j < 16; ++j) acc += ubuf[r][j] * Wo2[o * 16 + j];
        out[(size_t)(r0 + r) * 3 + o] = acc;
    }
}

extern "C" void kernel_launch(void* const* d_in, const int* in_sizes, int n_in,
                              void* d_out, int out_size, void* d_ws, size_t ws_size,
                              hipStream_t stream) {
    (void)in_sizes; (void)n_in; (void)d_ws; (void)ws_size; (void)out_size;
    const float* x   = (const float*)d_in[0];
    const float* Wi  = (const float*)d_in[1];
    const float* bi  = (const float*)d_in[2];
    const float* W1  = (const float*)d_in[3];
    const float* b1  = (const float*)d_in[4];
    const float* W2  = (const float*)d_in[5];
    const float* b2  = (const float*)d_in[6];
    const float* Wo1 = (const float*)d_in[7];
    const float* bo1 = (const float*)d_in[8];
    const float* Wo2 = (const float*)d_in[9];
    const float* bo2 = (const float*)d_in[10];
    cde_kernel<<<dim3(256), dim3(256), 0, stream>>>(x, Wi, bi, W1, b1, W2, b2,
                                                    Wo1, bo1, Wo2, bo2, (float*)d_out);
}